// Round 1
// baseline (418.999 us; speedup 1.0000x reference)
//
#include <hip/hip_runtime.h>
#include <stdint.h>
#include <stddef.h>

// Problem constants: b=4, n=1024, dim=512, heads=8, dh=64, inner*3=1536
// qkv bf16 workspace: q pre-scaled by SCALE/2 = 1/16 (exact power-of-2 fold)

typedef __attribute__((ext_vector_type(4))) float f32x4;
typedef __attribute__((ext_vector_type(8))) short bf16x8;

__device__ inline unsigned short f2bf(float f) {
    union { float f; uint32_t u; } cv; cv.f = f;
    uint32_t u = cv.u;
    return (unsigned short)((u + 0x7fffu + ((u >> 16) & 1u)) >> 16);
}
__device__ inline uint32_t packbf2(float lo, float hi) {
    return (uint32_t)f2bf(lo) | ((uint32_t)f2bf(hi) << 16);
}

// ---------------------------------------------------------------------------
// fp32 GEMM: C[M x NCOLS] = A[M x 512] * B[512 x NCOLS]
// 64m x 128n tile, 128 threads, 8x8 micro-tile.
// OUT_BF16: write bf16 with 1/16 scale on cols < 512 (the q block).
// ---------------------------------------------------------------------------
template<int NCOLS, bool OUT_BF16>
__global__ __launch_bounds__(128) void gemm_f32(const float* __restrict__ A,
                                                const float* __restrict__ Bw,
                                                void* __restrict__ outp) {
    constexpr int KD = 512;
    constexpr int NB = NCOLS / 128;
    __shared__ float As[8][64];     // [k][m] transposed
    __shared__ float Bs[8][128];    // [k][n]
    const int t = threadIdx.x;
    const int bm = blockIdx.x / NB;
    const int bn = blockIdx.x % NB;
    const int tx = t & 15, ty = t >> 4;

    f32x4 acc[8][2];
    {
        f32x4 z4 = {0.f, 0.f, 0.f, 0.f};
        #pragma unroll
        for (int i = 0; i < 8; i++) { acc[i][0] = z4; acc[i][1] = z4; }
    }

    const int am = t >> 1, af = t & 1;
    const float* aptr = A + (size_t)(bm * 64 + am) * KD + af * 4;

    for (int kt = 0; kt < KD / 8; kt++) {
        // stage A (64 rows x 8 k), transposed into As[k][m]
        f32x4 av = *(const f32x4*)(aptr + kt * 8);
        As[af * 4 + 0][am] = av.x;
        As[af * 4 + 1][am] = av.y;
        As[af * 4 + 2][am] = av.z;
        As[af * 4 + 3][am] = av.w;
        // stage B (8 k x 128 n)
        #pragma unroll
        for (int i = 0; i < 2; i++) {
            int id = t + 128 * i;
            int kk = id >> 5, n4 = id & 31;
            *(f32x4*)&Bs[kk][n4 * 4] =
                *(const f32x4*)(Bw + (size_t)(kt * 8 + kk) * NCOLS + bn * 128 + n4 * 4);
        }
        __syncthreads();
        #pragma unroll
        for (int k = 0; k < 8; k++) {
            f32x4 a0 = *(const f32x4*)&As[k][ty * 8];
            f32x4 a1 = *(const f32x4*)&As[k][ty * 8 + 4];
            f32x4 b0 = *(const f32x4*)&Bs[k][tx * 8];
            f32x4 b1 = *(const f32x4*)&Bs[k][tx * 8 + 4];
            #pragma unroll
            for (int i = 0; i < 4; i++) {
                acc[i][0] += a0[i] * b0;     acc[i][1] += a0[i] * b1;
                acc[i + 4][0] += a1[i] * b0; acc[i + 4][1] += a1[i] * b1;
            }
        }
        __syncthreads();
    }

    const int row0 = bm * 64 + ty * 8;
    const int col0 = bn * 128 + tx * 8;
    if (OUT_BF16) {
        short* ob = (short*)outp;
        const float sc = (bn < 4) ? 0.0625f : 1.0f;  // q block cols 0..511: * SCALE/2
        #pragma unroll
        for (int i = 0; i < 8; i++) {
            uint32_t* p = (uint32_t*)(ob + (size_t)(row0 + i) * 1536 + col0);
            f32x4 v0 = acc[i][0], v1 = acc[i][1];
            p[0] = packbf2(v0[0] * sc, v0[1] * sc);
            p[1] = packbf2(v0[2] * sc, v0[3] * sc);
            p[2] = packbf2(v1[0] * sc, v1[1] * sc);
            p[3] = packbf2(v1[2] * sc, v1[3] * sc);
        }
    } else {
        float* of = (float*)outp;
        #pragma unroll
        for (int i = 0; i < 8; i++) {
            *(f32x4*)(of + (size_t)(row0 + i) * NCOLS + col0) = acc[i][0];
            *(f32x4*)(of + (size_t)(row0 + i) * NCOLS + col0 + 4) = acc[i][1];
        }
    }
}

// ---------------------------------------------------------------------------
// Fused entmax-1.5 attention. One block = 8 query rows of one (b,h).
// qkv: bf16 [4096][1536], q pre-scaled by 1/16 so scores = sim/2 directly.
// Scores + PV via mfma_f32_16x16x32_bf16 (rows 8..15 of the 16-row MFMA frame
// are duplicates / zeros, ignored). Entmax threshold via Newton (20 iters) on
// register-resident z. Output fp32 [4096][512] in [b,n,h,d] order.
// ---------------------------------------------------------------------------
__global__ __launch_bounds__(256, 2) void attn_entmax(const short* __restrict__ qkv,
                                                      float* __restrict__ oheads) {
    __shared__ float z_s[8][1025];                   // raw scores, +1 pad breaks bank stride
    __shared__ __align__(16) unsigned char kvbuf[18432]; // K super [128][72]bf16 / V^T [64][68]u32 / osum
    __shared__ float taus[8];

    short* ks = (short*)kvbuf;
    uint32_t* vs = (uint32_t*)kvbuf;
    float* osum = (float*)kvbuf;

    const int t = threadIdx.x;
    const int lane = t & 63;
    const int wv = t >> 6;          // wave 0..3
    const int quad = lane >> 4;
    const int l16 = lane & 15;

    // XCD swizzle: XCD x gets head-batches 4x..4x+3 (K/V working set 1MB < 4MiB L2)
    const int xcd = blockIdx.x & 7;
    const int g = blockIdx.x >> 3;
    const int hb = xcd * 4 + (g >> 7);   // 0..31
    const int rt = g & 127;
    const int bb = hb >> 3, hh = hb & 7;
    const int r0 = rt * 8;

    // ---- Q A-frags from global (rows m>=8 duplicate rows 0..7; harmless) ----
    bf16x8 a0, a1;
    {
        const int qrow = r0 + (l16 & 7);
        const short* qp = qkv + (size_t)(bb * 1024 + qrow) * 1536 + hh * 64 + quad * 8;
        a0 = *(const bf16x8*)qp;
        a1 = *(const bf16x8*)(qp + 32);
    }

    // ---- scores: z_s[r][j] = (q . k)/16 = sim/2 ----
    for (int sup = 0; sup < 8; sup++) {
        #pragma unroll
        for (int i = 0; i < 4; i++) {
            int task = t + 256 * i;            // 1024 chunk tasks: 128 rows x 8 chunks
            int j = task >> 3, c = task & 7;
            const short* kp = qkv + (size_t)(bb * 1024 + sup * 128 + j) * 1536 + 512 + hh * 64 + c * 8;
            *(bf16x8*)(ks + j * 72 + c * 8) = *(const bf16x8*)kp;  // stride 72: bank rotation
        }
        __syncthreads();
        #pragma unroll
        for (int jj = 0; jj < 2; jj++) {
            int jt = wv + jj * 4;              // j-tile 0..7 within super
            const short* kb = ks + (jt * 16 + l16) * 72 + quad * 8;
            bf16x8 b0 = *(const bf16x8*)kb;
            bf16x8 b1 = *(const bf16x8*)(kb + 32);
            f32x4 acc = {0.f, 0.f, 0.f, 0.f};
            acc = __builtin_amdgcn_mfma_f32_16x16x32_bf16(a0, b0, acc, 0, 0, 0);
            acc = __builtin_amdgcn_mfma_f32_16x16x32_bf16(a1, b1, acc, 0, 0, 0);
            if (quad < 2) {                    // real rows 0..7 only
                const int jcol = sup * 128 + jt * 16 + l16;
                const int mrow = quad * 4;
                z_s[mrow + 0][jcol] = acc[0];
                z_s[mrow + 1][jcol] = acc[1];
                z_s[mrow + 2][jcol] = acc[2];
                z_s[mrow + 3][jcol] = acc[3];
            }
        }
        __syncthreads();
    }

    // ---- entmax threshold: Newton from below on f(tau)=sum relu(z-tau)^2 - 1 ----
    {
        const int row = t >> 5;     // 0..7
        const int slot = t & 31;
        float z[32];
        #pragma unroll
        for (int i = 0; i < 32; i++) z[i] = z_s[row][slot + 32 * i];
        float mx = z[0];
        #pragma unroll
        for (int i = 1; i < 32; i++) mx = fmaxf(mx, z[i]);
        #pragma unroll
        for (int s = 16; s > 0; s >>= 1) mx = fmaxf(mx, __shfl_xor(mx, s, 32));
        #pragma unroll
        for (int i = 0; i < 32; i++) z[i] -= mx;
        float tau = -1.0f;          // f(-1) >= 0 since max z = 0
        for (int it = 0; it < 20; it++) {
            float s1 = 0.f, s2 = 0.f;
            #pragma unroll
            for (int i = 0; i < 32; i++) {
                float r = fmaxf(z[i] - tau, 0.f);
                s1 += r;
                s2 = fmaf(r, r, s2);
            }
            #pragma unroll
            for (int s = 16; s > 0; s >>= 1) {
                s1 += __shfl_xor(s1, s, 32);
                s2 += __shfl_xor(s2, s, 32);
            }
            tau += (s2 - 1.0f) / (2.0f * s1);   // f' <= -2 at root: well-conditioned
        }
        if (slot == 0) taus[row] = mx + tau;    // threshold on raw-z scale
    }
    __syncthreads();

    // ---- PV: O[r][d] = sum_j relu(z-T)^2 * V[j][d] ----
    const float Tmy = taus[l16 & 7];
    f32x4 oacc[4];
    {
        f32x4 z4 = {0.f, 0.f, 0.f, 0.f};
        oacc[0] = z4; oacc[1] = z4; oacc[2] = z4; oacc[3] = z4;
    }
    for (int sup = 0; sup < 8; sup++) {
        __syncthreads();   // previous-super V reads (and K phase) complete
        // stage V transposed + pair-packed: vs[d][jpair] = (v[2jp][d], v[2jp+1][d])
        #pragma unroll
        for (int i2 = 0; i2 < 2; i2++) {
            int task = t + 256 * i2;           // 512 tasks: 8 d-chunks x 64 j-pairs
            int c = task & 7, jp = task >> 3;
            const short* vp = qkv + (size_t)(bb * 1024 + sup * 128 + jp * 2) * 1536 + 1024 + hh * 64 + c * 8;
            bf16x8 v0 = *(const bf16x8*)vp;
            bf16x8 v1 = *(const bf16x8*)(vp + 1536);
            #pragma unroll
            for (int kk = 0; kk < 8; kk++) {
                vs[(c * 8 + kk) * 68 + jp] =
                    (uint32_t)(uint16_t)v0[kk] | ((uint32_t)(uint16_t)v1[kk] << 16);
            }
        }
        __syncthreads();
        // P A-frag for this wave's k-chunk (32 j's), rows >= 8 zeroed
        bf16x8 pf;
        const int mrow = l16 & 7;
        #pragma unroll
        for (int jj2 = 0; jj2 < 8; jj2++) {
            int j = sup * 128 + wv * 32 + quad * 8 + jj2;
            float r = fmaxf(z_s[mrow][j] - Tmy, 0.f);
            float p = (l16 < 8) ? r * r : 0.f;
            pf[jj2] = (short)f2bf(p);
        }
        // 4 n-tiles cover d=0..63; wave accumulates its j-quarter
        #pragma unroll
        for (int nt = 0; nt < 4; nt++) {
            const uint32_t* vb = vs + (nt * 16 + l16) * 68 + wv * 16 + quad * 4;
            bf16x8 bv = *(const bf16x8*)vb;
            oacc[nt] = __builtin_amdgcn_mfma_f32_16x16x32_bf16(pf, bv, oacc[nt], 0, 0, 0);
        }
    }
    __syncthreads();
    // cross-wave reduction of O partials via LDS (overlay on kvbuf)
    if (quad < 2) {
        #pragma unroll
        for (int nt = 0; nt < 4; nt++) {
            #pragma unroll
            for (int rg = 0; rg < 4; rg++) {
                osum[(wv * 8 + quad * 4 + rg) * 64 + nt * 16 + l16] = oacc[nt][rg];
            }
        }
    }
    __syncthreads();
    #pragma unroll
    for (int i = 0; i < 2; i++) {
        int idx = t + 256 * i;     // 512 outputs: 8 rows x 64 d
        int r = idx >> 6, d = idx & 63;
        float s = osum[r * 64 + d] + osum[(8 + r) * 64 + d]
                + osum[(16 + r) * 64 + d] + osum[(24 + r) * 64 + d];
        oheads[(size_t)(bb * 1024 + r0 + r) * 512 + hh * 64 + d] = s;
    }
}

// ---------------------------------------------------------------------------
extern "C" void kernel_launch(void* const* d_in, const int* in_sizes, int n_in,
                              void* d_out, int out_size, void* d_ws, size_t ws_size,
                              hipStream_t stream) {
    (void)in_sizes; (void)n_in; (void)out_size; (void)ws_size;
    const float* x     = (const float*)d_in[0];   // [4,1024,512]
    const float* w_qkv = (const float*)d_in[1];   // [512,1536]
    const float* w_out = (const float*)d_in[2];   // [512,512]
    float* out = (float*)d_out;                   // [4,1024,512] fp32

    short* qkv_b  = (short*)d_ws;                                   // 4096*1536 bf16 = 12.6 MB
    float* oheads = (float*)((char*)d_ws + (size_t)4096 * 1536 * 2); // 4096*512 fp32 = 8.4 MB

    // 1) qkv = x @ w_qkv  (bf16 out, q scaled by 1/16)
    gemm_f32<1536, true><<<dim3(64 * 12), dim3(128), 0, stream>>>(x, w_qkv, (void*)qkv_b);
    // 2) fused entmax-1.5 attention -> oheads [b,n,h,d]
    attn_entmax<<<dim3(4096), dim3(256), 0, stream>>>(qkv_b, oheads);
    // 3) out = oheads @ w_out (fp32)
    gemm_f32<512, false><<<dim3(64 * 4), dim3(128), 0, stream>>>(oheads, w_out, (void*)out);
}

// Round 2
// 200.008 us; speedup vs baseline: 2.0949x; 2.0949x over previous
//
#include <hip/hip_runtime.h>
#include <stdint.h>
#include <stddef.h>

// b=4, n=1024, dim=512, heads=8, dh=64. qkv bf16 ws: q pre-scaled by 1/16.

typedef __attribute__((ext_vector_type(4))) float f32x4;
typedef __attribute__((ext_vector_type(8))) short bf16x8;
typedef __attribute__((ext_vector_type(4))) uint32_t u32x4;
typedef __attribute__((ext_vector_type(2))) uint32_t u32x2;

__device__ inline unsigned short f2bf(float f) {
    union { float f; uint32_t u; } cv; cv.f = f;
    uint32_t u = cv.u;
    return (unsigned short)((u + 0x7fffu + ((u >> 16) & 1u)) >> 16);
}
__device__ inline uint32_t packbf2(float lo, float hi) {
    return (uint32_t)f2bf(lo) | ((uint32_t)f2bf(hi) << 16);
}
__device__ inline void gl_lds16(const short* g, short* l) {
    __builtin_amdgcn_global_load_lds(
        (const __attribute__((address_space(1))) void*)g,
        (__attribute__((address_space(3))) void*)l, 16, 0, 0);
}

// ---------------------------------------------------------------------------
// convert: x fp32 -> bf16; w_qkv [512][1536] -> wqkvt [1536][512] bf16;
//          w_out [512][512] -> woutt [512][512] bf16 (transposed)
// ---------------------------------------------------------------------------
__global__ __launch_bounds__(256) void convert_all(const float* __restrict__ x,
                                                   const float* __restrict__ wqkv,
                                                   const float* __restrict__ wout,
                                                   short* __restrict__ xb,
                                                   short* __restrict__ wqkvt,
                                                   short* __restrict__ woutt) {
    __shared__ float tl[32][33];
    const int bid = blockIdx.x;
    const int t = threadIdx.x;
    if (bid < 1024) {                       // x: 2M elems, 2048/block
        int base = bid * 2048 + t * 8;
        f32x4 v0 = *(const f32x4*)(x + base);
        f32x4 v1 = *(const f32x4*)(x + base + 4);
        u32x4 o = {packbf2(v0[0], v0[1]), packbf2(v0[2], v0[3]),
                   packbf2(v1[0], v1[1]), packbf2(v1[2], v1[3])};
        *(u32x4*)(xb + base) = o;
        return;
    }
    const float* src; short* dst; int NC, tn, tk;
    if (bid < 1024 + 768) {                 // w_qkv transpose: 48 x 16 tiles
        int idx = bid - 1024; tn = idx % 48; tk = idx / 48; src = wqkv; dst = wqkvt; NC = 1536;
    } else {                                // w_out transpose: 16 x 16 tiles
        int idx = bid - 1792; tn = idx % 16; tk = idx / 16; src = wout; dst = woutt; NC = 512;
    }
    const int row = t >> 3, c4 = (t & 7) * 4;
    f32x4 v = *(const f32x4*)(src + (size_t)(tk * 32 + row) * NC + tn * 32 + c4);
    tl[row][c4 + 0] = v[0]; tl[row][c4 + 1] = v[1];
    tl[row][c4 + 2] = v[2]; tl[row][c4 + 3] = v[3];
    __syncthreads();
    float a = tl[c4 + 0][row], b = tl[c4 + 1][row];
    float c = tl[c4 + 2][row], d = tl[c4 + 3][row];
    u32x2 o = {packbf2(a, b), packbf2(c, d)};
    *(u32x2*)(dst + (size_t)(tn * 32 + row) * 512 + tk * 32 + c4) = o;
}

// ---------------------------------------------------------------------------
// bf16 MFMA GEMM: C[M x NB*128] = A[M x 512] * Bt[NB*128 x 512]^T
// 128x128 tile, 256 thr (4 waves, each 64x64), BK=32, global_load_lds(16B).
// ---------------------------------------------------------------------------
template<int NB, bool QSCALE, bool OUTF32>
__global__ __launch_bounds__(256) void gemm_bf16(const short* __restrict__ A,
                                                 const short* __restrict__ Bt,
                                                 void* __restrict__ outp) {
    __shared__ __align__(16) short As[128 * 32];
    __shared__ __align__(16) short Bs[128 * 32];
    const int t = threadIdx.x;
    const int lane = t & 63;
    const int wv = t >> 6;
    const int quad = lane >> 4;
    const int l16 = lane & 15;
    const int bm = blockIdx.x / NB;
    const int bn = blockIdx.x % NB;
    const int wm = (wv & 1) * 64, wn = (wv >> 1) * 64;

    f32x4 acc[4][4];
    #pragma unroll
    for (int i = 0; i < 4; i++)
        #pragma unroll
        for (int j = 0; j < 4; j++) acc[i][j] = (f32x4){0.f, 0.f, 0.f, 0.f};

    const int srow = lane >> 2;             // 0..15
    const int scol = (lane & 3) * 8;        // shorts

    for (int kt = 0; kt < 16; kt++) {
        #pragma unroll
        for (int cc = 0; cc < 2; cc++) {
            int chunk = wv + cc * 4;        // 0..7, 16 rows each
            const short* ga = A + (size_t)(bm * 128 + chunk * 16 + srow) * 512 + kt * 32 + scol;
            gl_lds16(ga, As + chunk * 512);
            const short* gb = Bt + (size_t)(bn * 128 + chunk * 16 + srow) * 512 + kt * 32 + scol;
            gl_lds16(gb, Bs + chunk * 512);
        }
        __syncthreads();
        bf16x8 af[4], bfr[4];
        #pragma unroll
        for (int mi = 0; mi < 4; mi++)
            af[mi] = *(const bf16x8*)(As + (wm + mi * 16 + l16) * 32 + quad * 8);
        #pragma unroll
        for (int ni = 0; ni < 4; ni++)
            bfr[ni] = *(const bf16x8*)(Bs + (wn + ni * 16 + l16) * 32 + quad * 8);
        #pragma unroll
        for (int mi = 0; mi < 4; mi++)
            #pragma unroll
            for (int ni = 0; ni < 4; ni++)
                acc[mi][ni] = __builtin_amdgcn_mfma_f32_16x16x32_bf16(af[mi], bfr[ni], acc[mi][ni], 0, 0, 0);
        __syncthreads();
    }
    const int N = NB * 128;
    if (OUTF32) {
        float* of = (float*)outp;
        #pragma unroll
        for (int mi = 0; mi < 4; mi++)
            #pragma unroll
            for (int ni = 0; ni < 4; ni++)
                #pragma unroll
                for (int rg = 0; rg < 4; rg++)
                    of[(size_t)(bm * 128 + wm + mi * 16 + quad * 4 + rg) * N + bn * 128 + wn + ni * 16 + l16]
                        = acc[mi][ni][rg];
    } else {
        short* ob = (short*)outp;
        const float sc = (QSCALE && bn < 4) ? 0.0625f : 1.0f;
        #pragma unroll
        for (int mi = 0; mi < 4; mi++)
            #pragma unroll
            for (int ni = 0; ni < 4; ni++)
                #pragma unroll
                for (int rg = 0; rg < 4; rg++)
                    ob[(size_t)(bm * 128 + wm + mi * 16 + quad * 4 + rg) * N + bn * 128 + wn + ni * 16 + l16]
                        = (short)f2bf(acc[mi][ni][rg] * sc);
    }
}

// ---------------------------------------------------------------------------
// Fused entmax-1.5 attention, 16 query rows/block, z in registers.
// qkv bf16 [4096][1536] (q pre-scaled 1/16). Output oheads bf16 [4096][512].
// ---------------------------------------------------------------------------
__global__ __launch_bounds__(256, 3) void attn_entmax(const short* __restrict__ qkv,
                                                      short* __restrict__ oheads) {
    __shared__ __align__(16) unsigned char kvbuf[17408]; // K [128][64]bf16 / V^T u32 [64][68] / osum
    __shared__ __align__(16) short P_lds[16 * 1032];     // P bf16, row stride 1032
    __shared__ float redbuf[2][4][16][2];                // ping-pong cross-wave reduce

    short* ks = (short*)kvbuf;
    uint32_t* vs = (uint32_t*)kvbuf;
    float* osum = (float*)kvbuf;

    const int t = threadIdx.x;
    const int lane = t & 63;
    const int wv = t >> 6;
    const int quad = lane >> 4;
    const int l16 = lane & 15;

    const int xcd = blockIdx.x & 7;
    const int g = blockIdx.x >> 3;
    const int hb = xcd * 4 + (g >> 6);      // 0..31
    const int rt = g & 63;
    const int bb = hb >> 3, hh = hb & 7;
    const int r0 = rt * 16;

    // Q A-frags (16 real rows)
    bf16x8 a0, a1;
    {
        const short* qp = qkv + (size_t)(bb * 1024 + r0 + l16) * 1536 + hh * 64 + quad * 8;
        a0 = *(const bf16x8*)qp;
        a1 = *(const bf16x8*)(qp + 32);
    }

    // ---- scores into registers: zf[fi] , fi = sup*2+jj; cols = sup*128+(wv+4*jj)*16+l16,
    //      rows = quad*4+rg (C-layout) ----
    f32x4 zf[16];
    #pragma unroll
    for (int sup = 0; sup < 8; sup++) {
        #pragma unroll
        for (int cc = 0; cc < 4; cc++) {
            int chunk = wv * 4 + cc;        // 16 chunks x 8 rows
            int row = chunk * 8 + (lane >> 3);
            const short* gp = qkv + (size_t)(bb * 1024 + sup * 128 + row) * 1536 + 512 + hh * 64 + (lane & 7) * 8;
            gl_lds16(gp, ks + chunk * 512);
        }
        __syncthreads();
        #pragma unroll
        for (int jj = 0; jj < 2; jj++) {
            int jt = wv + jj * 4;
            const short* kb = ks + (jt * 16 + l16) * 64 + quad * 8;
            bf16x8 b0 = *(const bf16x8*)kb;
            bf16x8 b1 = *(const bf16x8*)(kb + 32);
            f32x4 acc = {0.f, 0.f, 0.f, 0.f};
            acc = __builtin_amdgcn_mfma_f32_16x16x32_bf16(a1, b1, acc, 0, 0, 0);
            acc = __builtin_amdgcn_mfma_f32_16x16x32_bf16(a0, b0, acc, 0, 0, 0);
            zf[sup * 2 + jj] = acc;
        }
        __syncthreads();
    }

    // ---- row max (over 16 frames, 16 lanes, 4 waves) + shift ----
    float mx[4];
    #pragma unroll
    for (int rg = 0; rg < 4; rg++) {
        float m = zf[0][rg];
        #pragma unroll
        for (int fi = 1; fi < 16; fi++) m = fmaxf(m, zf[fi][rg]);
        #pragma unroll
        for (int s = 1; s < 16; s <<= 1) m = fmaxf(m, __shfl_xor(m, s, 64));
        mx[rg] = m;
    }
    if (l16 == 0) {
        #pragma unroll
        for (int rg = 0; rg < 4; rg++) redbuf[0][wv][quad * 4 + rg][0] = mx[rg];
    }
    __syncthreads();
    #pragma unroll
    for (int rg = 0; rg < 4; rg++) {
        float m = fmaxf(fmaxf(redbuf[0][0][quad * 4 + rg][0], redbuf[0][1][quad * 4 + rg][0]),
                        fmaxf(redbuf[0][2][quad * 4 + rg][0], redbuf[0][3][quad * 4 + rg][0]));
        #pragma unroll
        for (int fi = 0; fi < 16; fi++) zf[fi][rg] -= m;
    }
    __syncthreads();   // protect redbuf[0] before Newton iter 0 writes

    // ---- Newton from below on f(tau) = sum relu(z-tau)^2 - 1 (monotone, quadratic) ----
    float tau[4] = {-1.f, -1.f, -1.f, -1.f};
    int pp = 0;
    for (int it = 0; it < 12; it++) {
        float s1[4] = {0.f, 0.f, 0.f, 0.f}, s2[4] = {0.f, 0.f, 0.f, 0.f};
        #pragma unroll
        for (int fi = 0; fi < 16; fi++)
            #pragma unroll
            for (int rg = 0; rg < 4; rg++) {
                float r = fmaxf(zf[fi][rg] - tau[rg], 0.f);
                s1[rg] += r;
                s2[rg] = fmaf(r, r, s2[rg]);
            }
        #pragma unroll
        for (int s = 1; s < 16; s <<= 1)
            #pragma unroll
            for (int rg = 0; rg < 4; rg++) {
                s1[rg] += __shfl_xor(s1[rg], s, 64);
                s2[rg] += __shfl_xor(s2[rg], s, 64);
            }
        if (l16 == 0) {
            #pragma unroll
            for (int rg = 0; rg < 4; rg++) {
                redbuf[pp][wv][quad * 4 + rg][0] = s1[rg];
                redbuf[pp][wv][quad * 4 + rg][1] = s2[rg];
            }
        }
        __syncthreads();
        #pragma unroll
        for (int rg = 0; rg < 4; rg++) {
            int rr = quad * 4 + rg;
            float S1 = redbuf[pp][0][rr][0] + redbuf[pp][1][rr][0]
                     + redbuf[pp][2][rr][0] + redbuf[pp][3][rr][0];
            float S2 = redbuf[pp][0][rr][1] + redbuf[pp][1][rr][1]
                     + redbuf[pp][2][rr][1] + redbuf[pp][3][rr][1];
            tau[rg] += (S2 - 1.f) * 0.5f * __builtin_amdgcn_rcpf(S1);
        }
        pp ^= 1;
    }

    // ---- P = relu(z - tau)^2 -> P_lds (bf16, A-operand layout [row][j]) ----
    #pragma unroll
    for (int fi = 0; fi < 16; fi++) {
        int sup = fi >> 1, jj = fi & 1;
        int jbase = sup * 128 + (wv + jj * 4) * 16;
        #pragma unroll
        for (int rg = 0; rg < 4; rg++) {
            float r = fmaxf(zf[fi][rg] - tau[rg], 0.f);
            P_lds[(quad * 4 + rg) * 1032 + jbase + l16] = (short)f2bf(r * r);
        }
    }
    __syncthreads();

    // ---- PV: O[r][d] += P[r][j] V[j][d], wave w covers j-chunk w*32 per super ----
    f32x4 oacc[4];
    #pragma unroll
    for (int nt = 0; nt < 4; nt++) oacc[nt] = (f32x4){0.f, 0.f, 0.f, 0.f};
    #pragma unroll
    for (int sup = 0; sup < 8; sup++) {
        __syncthreads();   // protect vs from previous super's reads
        #pragma unroll
        for (int i2 = 0; i2 < 2; i2++) {
            int jp = wv * 16 + l16;
            int c = ((t >> 4) & 3) + 4 * i2;
            const short* vp = qkv + (size_t)(bb * 1024 + sup * 128 + jp * 2) * 1536 + 1024 + hh * 64 + c * 8;
            bf16x8 v0 = *(const bf16x8*)vp;
            bf16x8 v1 = *(const bf16x8*)(vp + 1536);
            #pragma unroll
            for (int kk = 0; kk < 8; kk++)
                vs[(c * 8 + kk) * 68 + jp] =
                    (uint32_t)(uint16_t)v0[kk] | ((uint32_t)(uint16_t)v1[kk] << 16);
        }
        __syncthreads();
        bf16x8 pf = *(const bf16x8*)(P_lds + l16 * 1032 + sup * 128 + wv * 32 + quad * 8);
        #pragma unroll
        for (int nt = 0; nt < 4; nt++) {
            bf16x8 bv = *(const bf16x8*)(vs + (nt * 16 + l16) * 68 + wv * 16 + quad * 4);
            oacc[nt] = __builtin_amdgcn_mfma_f32_16x16x32_bf16(pf, bv, oacc[nt], 0, 0, 0);
        }
    }
    __syncthreads();

    // ---- cross-wave O reduction + bf16 store ----
    #pragma unroll
    for (int nt = 0; nt < 4; nt++)
        #pragma unroll
        for (int rg = 0; rg < 4; rg++)
            osum[(wv * 16 + quad * 4 + rg) * 68 + nt * 16 + l16] = oacc[nt][rg];
    __syncthreads();
    #pragma unroll
    for (int i = 0; i < 2; i++) {
        int idx = t + 256 * i;              // 512 col-pair tasks
        int r = idx >> 5, dp = idx & 31;
        float e0 = 0.f, e1 = 0.f;
        #pragma unroll
        for (int w = 0; w < 4; w++) {
            e0 += osum[(w * 16 + r) * 68 + dp * 2];
            e1 += osum[(w * 16 + r) * 68 + dp * 2 + 1];
        }
        *(uint32_t*)(oheads + (size_t)(bb * 1024 + r0 + r) * 512 + hh * 64 + dp * 2) = packbf2(e0, e1);
    }
}

// ---------------------------------------------------------------------------
extern "C" void kernel_launch(void* const* d_in, const int* in_sizes, int n_in,
                              void* d_out, int out_size, void* d_ws, size_t ws_size,
                              hipStream_t stream) {
    (void)in_sizes; (void)n_in; (void)out_size; (void)ws_size;
    const float* x     = (const float*)d_in[0];
    const float* w_qkv = (const float*)d_in[1];
    const float* w_out = (const float*)d_in[2];
    float* out = (float*)d_out;

    char* ws = (char*)d_ws;
    short* qkv_b  = (short*)(ws);                        // 12,582,912 B
    short* ohead  = (short*)(ws + 12582912);             //  4,194,304 B
    short* xb     = (short*)(ws + 16777216);             //  4,194,304 B
    short* wqkvt  = (short*)(ws + 20971520);             //  1,572,864 B
    short* woutt  = (short*)(ws + 22544384);             //    524,288 B

    convert_all<<<dim3(2048), dim3(256), 0, stream>>>(x, w_qkv, w_out, xb, wqkvt, woutt);
    gemm_bf16<12, true, false><<<dim3(32 * 12), dim3(256), 0, stream>>>(xb, wqkvt, (void*)qkv_b);
    attn_entmax<<<dim3(2048), dim3(256), 0, stream>>>(qkv_b, ohead);
    gemm_bf16<4, false, true><<<dim3(32 * 4), dim3(256), 0, stream>>>(ohead, woutt, (void*)out);
}

// Round 3
// 181.129 us; speedup vs baseline: 2.3133x; 1.1042x over previous
//
#include <hip/hip_runtime.h>
#include <stdint.h>
#include <stddef.h>

// b=4, n=1024, dim=512, heads=8, dh=64. qkv ws: [4096][1024] bf16 = Q|K only,
// q pre-scaled by 1/16; V written transposed to vt[b][h][64][1024] bf16.

typedef __attribute__((ext_vector_type(4))) float f32x4;
typedef __attribute__((ext_vector_type(8))) short bf16x8;
typedef __attribute__((ext_vector_type(4))) uint32_t u32x4;
typedef __attribute__((ext_vector_type(2))) uint32_t u32x2;

__device__ inline unsigned short f2bf(float f) {
    union { float f; uint32_t u; } cv; cv.f = f;
    uint32_t u = cv.u;
    return (unsigned short)((u + 0x7fffu + ((u >> 16) & 1u)) >> 16);
}
__device__ inline uint32_t packbf2(float lo, float hi) {
    return (uint32_t)f2bf(lo) | ((uint32_t)f2bf(hi) << 16);
}
__device__ inline void gl_lds16(const short* g, short* l) {
    __builtin_amdgcn_global_load_lds(
        (const __attribute__((address_space(1))) void*)g,
        (__attribute__((address_space(3))) void*)l, 16, 0, 0);
}

// ---------------------------------------------------------------------------
// convert: x fp32 -> bf16; w_qkv [512][1536] -> wqkvt [1536][512] bf16 (T);
//          w_out [512][512] -> woutt [512][512] bf16 (T)
// ---------------------------------------------------------------------------
__global__ __launch_bounds__(256) void convert_all(const float* __restrict__ x,
                                                   const float* __restrict__ wqkv,
                                                   const float* __restrict__ wout,
                                                   short* __restrict__ xb,
                                                   short* __restrict__ wqkvt,
                                                   short* __restrict__ woutt) {
    __shared__ float tl[32][33];
    const int bid = blockIdx.x;
    const int t = threadIdx.x;
    if (bid < 1024) {                       // x: 2M elems, 2048/block
        int base = bid * 2048 + t * 8;
        f32x4 v0 = *(const f32x4*)(x + base);
        f32x4 v1 = *(const f32x4*)(x + base + 4);
        u32x4 o = {packbf2(v0[0], v0[1]), packbf2(v0[2], v0[3]),
                   packbf2(v1[0], v1[1]), packbf2(v1[2], v1[3])};
        *(u32x4*)(xb + base) = o;
        return;
    }
    const float* src; short* dst; int NC, tn, tk;
    if (bid < 1024 + 768) {                 // w_qkv transpose: 48 x 16 tiles
        int idx = bid - 1024; tn = idx % 48; tk = idx / 48; src = wqkv; dst = wqkvt; NC = 1536;
    } else {                                // w_out transpose: 16 x 16 tiles
        int idx = bid - 1792; tn = idx % 16; tk = idx / 16; src = wout; dst = woutt; NC = 512;
    }
    const int row = t >> 3, c4 = (t & 7) * 4;
    f32x4 v = *(const f32x4*)(src + (size_t)(tk * 32 + row) * NC + tn * 32 + c4);
    tl[row][c4 + 0] = v[0]; tl[row][c4 + 1] = v[1];
    tl[row][c4 + 2] = v[2]; tl[row][c4 + 3] = v[3];
    __syncthreads();
    float a = tl[c4 + 0][row], b = tl[c4 + 1][row];
    float c = tl[c4 + 2][row], d = tl[c4 + 3][row];
    u32x2 o = {packbf2(a, b), packbf2(c, d)};
    *(u32x2*)(dst + (size_t)(tn * 32 + row) * 512 + tk * 32 + c4) = o;
}

// ---------------------------------------------------------------------------
// bf16 MFMA GEMM: 64m x 128n tile, 256 thr (4 waves of 32x64), BK=32.
// MODE 0: out = qkv buffer [M][1024] bf16 (bn<4: *1/16 q; bn in 4..7: k) and
//         vt [32][64][1024] bf16 transposed (bn>=8 = V columns).
// MODE 1: out = fp32 row-major [M][512].
// ---------------------------------------------------------------------------
template<int NB, int MODE>
__global__ __launch_bounds__(256) void gemm_bf16(const short* __restrict__ A,
                                                 const short* __restrict__ Bt,
                                                 void* __restrict__ outp,
                                                 short* __restrict__ vt) {
    __shared__ __align__(16) short As[64 * 32];
    __shared__ __align__(16) short Bs[128 * 32];
    const int t = threadIdx.x;
    const int lane = t & 63;
    const int wv = t >> 6;
    const int quad = lane >> 4;
    const int l16 = lane & 15;
    const int bm = blockIdx.x / NB;
    const int bn = blockIdx.x % NB;
    const int wm = (wv & 1) * 32, wn = (wv >> 1) * 64;

    f32x4 acc[2][4];
    #pragma unroll
    for (int i = 0; i < 2; i++)
        #pragma unroll
        for (int j = 0; j < 4; j++) acc[i][j] = (f32x4){0.f, 0.f, 0.f, 0.f};

    const int sr = t >> 2, sc = (t & 3) * 8;

    for (int kt = 0; kt < 16; kt++) {
        gl_lds16(A + (size_t)(bm * 64 + sr) * 512 + kt * 32 + sc, As + t * 8);
        #pragma unroll
        for (int i = 0; i < 2; i++)
            gl_lds16(Bt + (size_t)(bn * 128 + 64 * i + sr) * 512 + kt * 32 + sc,
                     Bs + 64 * i * 32 + t * 8);
        __syncthreads();
        bf16x8 af[2], bfr[4];
        #pragma unroll
        for (int mi = 0; mi < 2; mi++)
            af[mi] = *(const bf16x8*)(As + (wm + mi * 16 + l16) * 32 + quad * 8);
        #pragma unroll
        for (int ni = 0; ni < 4; ni++)
            bfr[ni] = *(const bf16x8*)(Bs + (wn + ni * 16 + l16) * 32 + quad * 8);
        #pragma unroll
        for (int mi = 0; mi < 2; mi++)
            #pragma unroll
            for (int ni = 0; ni < 4; ni++)
                acc[mi][ni] = __builtin_amdgcn_mfma_f32_16x16x32_bf16(af[mi], bfr[ni], acc[mi][ni], 0, 0, 0);
        __syncthreads();
    }

    if (MODE == 0) {
        short* ob = (short*)outp;
        if (bn < 8) {
            const float scq = (bn < 4) ? 0.0625f : 1.0f;
            #pragma unroll
            for (int mi = 0; mi < 2; mi++)
                #pragma unroll
                for (int ni = 0; ni < 4; ni++)
                    #pragma unroll
                    for (int rg = 0; rg < 4; rg++)
                        ob[(size_t)(bm * 64 + wm + mi * 16 + quad * 4 + rg) * 1024
                           + bn * 128 + wn + ni * 16 + l16] = (short)f2bf(acc[mi][ni][rg] * scq);
        } else {
            #pragma unroll
            for (int mi = 0; mi < 2; mi++) {
                int rowb = bm * 64 + wm + mi * 16 + quad * 4;
                int bbb = rowb >> 10, j = rowb & 1023;
                #pragma unroll
                for (int ni = 0; ni < 4; ni++) {
                    int vcol = bn * 128 + wn + ni * 16 + l16 - 1024;   // 0..511
                    int hh = vcol >> 6, dd = vcol & 63;
                    u32x2 pk = {packbf2(acc[mi][ni][0], acc[mi][ni][1]),
                                packbf2(acc[mi][ni][2], acc[mi][ni][3])};
                    *(u32x2*)(vt + ((size_t)((bbb * 8 + hh) * 64 + dd)) * 1024 + j) = pk;
                }
            }
        }
    } else {
        float* of = (float*)outp;
        #pragma unroll
        for (int mi = 0; mi < 2; mi++)
            #pragma unroll
            for (int ni = 0; ni < 4; ni++)
                #pragma unroll
                for (int rg = 0; rg < 4; rg++)
                    of[(size_t)(bm * 64 + wm + mi * 16 + quad * 4 + rg) * 512
                       + bn * 128 + wn + ni * 16 + l16] = acc[mi][ni][rg];
    }
}

// ---------------------------------------------------------------------------
// Fused entmax-1.5 attention, 16 query rows/block, z in registers.
// K and V^T B-fragments streamed directly from global (L2-resident via XCD
// swizzle) — no LDS staging, no barriers in the MFMA loops.
// ---------------------------------------------------------------------------
__global__ __launch_bounds__(256, 3) void attn_entmax(const short* __restrict__ qkv,
                                                      const short* __restrict__ vt,
                                                      short* __restrict__ oheads) {
    __shared__ __align__(16) short P_lds[16 * 1032];     // 33 KB; osum overlays after PV
    __shared__ float redbuf[2][4][16][2];

    float* osum = (float*)P_lds;

    const int t = threadIdx.x;
    const int lane = t & 63;
    const int wv = t >> 6;
    const int quad = lane >> 4;
    const int l16 = lane & 15;

    const int xcd = blockIdx.x & 7;
    const int g = blockIdx.x >> 3;
    const int hb = xcd * 4 + (g >> 6);      // 0..31
    const int rt = g & 63;
    const int bb = hb >> 3, hh = hb & 7;
    const int r0 = rt * 16;

    // Q A-frags (16 real rows); q pre-scaled by 1/16 so z = sim/2 directly
    bf16x8 a0, a1;
    {
        const short* qp = qkv + (size_t)(bb * 1024 + r0 + l16) * 1024 + hh * 64 + quad * 8;
        a0 = *(const bf16x8*)qp;
        a1 = *(const bf16x8*)(qp + 32);
    }

    // ---- scores straight from global K: zf[fi], fi=sup*2+jj,
    //      cols = sup*128 + (wv+4*jj)*16 + l16, rows = quad*4+rg ----
    f32x4 zf[16];
    const short* kb0 = qkv + (size_t)(bb * 1024) * 1024 + 512 + hh * 64 + quad * 8;
    #pragma unroll
    for (int fi = 0; fi < 16; fi++) {
        int sup = fi >> 1, jj = fi & 1;
        int j0 = sup * 128 + (wv + 4 * jj) * 16 + l16;
        const short* kp = kb0 + (size_t)j0 * 1024;
        bf16x8 b0 = *(const bf16x8*)kp;
        bf16x8 b1 = *(const bf16x8*)(kp + 32);
        f32x4 acc = {0.f, 0.f, 0.f, 0.f};
        acc = __builtin_amdgcn_mfma_f32_16x16x32_bf16(a0, b0, acc, 0, 0, 0);
        acc = __builtin_amdgcn_mfma_f32_16x16x32_bf16(a1, b1, acc, 0, 0, 0);
        zf[fi] = acc;
    }

    // ---- row max + shift ----
    float mx[4];
    #pragma unroll
    for (int rg = 0; rg < 4; rg++) {
        float m = zf[0][rg];
        #pragma unroll
        for (int fi = 1; fi < 16; fi++) m = fmaxf(m, zf[fi][rg]);
        #pragma unroll
        for (int s = 1; s < 16; s <<= 1) m = fmaxf(m, __shfl_xor(m, s, 64));
        mx[rg] = m;
    }
    if (l16 == 0) {
        #pragma unroll
        for (int rg = 0; rg < 4; rg++) redbuf[0][wv][quad * 4 + rg][0] = mx[rg];
    }
    __syncthreads();
    #pragma unroll
    for (int rg = 0; rg < 4; rg++) {
        float m = fmaxf(fmaxf(redbuf[0][0][quad * 4 + rg][0], redbuf[0][1][quad * 4 + rg][0]),
                        fmaxf(redbuf[0][2][quad * 4 + rg][0], redbuf[0][3][quad * 4 + rg][0]));
        #pragma unroll
        for (int fi = 0; fi < 16; fi++) zf[fi][rg] -= m;
    }
    __syncthreads();   // protect redbuf[0] before Newton iter 0 writes

    // ---- Newton from below on f(tau)=sum relu(z-tau)^2 - 1 ----
    float tau[4] = {-1.f, -1.f, -1.f, -1.f};
    int pp = 0;
    for (int it = 0; it < 12; it++) {
        float s1[4] = {0.f, 0.f, 0.f, 0.f}, s2[4] = {0.f, 0.f, 0.f, 0.f};
        #pragma unroll
        for (int fi = 0; fi < 16; fi++)
            #pragma unroll
            for (int rg = 0; rg < 4; rg++) {
                float r = fmaxf(zf[fi][rg] - tau[rg], 0.f);
                s1[rg] += r;
                s2[rg] = fmaf(r, r, s2[rg]);
            }
        #pragma unroll
        for (int s = 1; s < 16; s <<= 1)
            #pragma unroll
            for (int rg = 0; rg < 4; rg++) {
                s1[rg] += __shfl_xor(s1[rg], s, 64);
                s2[rg] += __shfl_xor(s2[rg], s, 64);
            }
        if (l16 == 0) {
            #pragma unroll
            for (int rg = 0; rg < 4; rg++) {
                redbuf[pp][wv][quad * 4 + rg][0] = s1[rg];
                redbuf[pp][wv][quad * 4 + rg][1] = s2[rg];
            }
        }
        __syncthreads();
        #pragma unroll
        for (int rg = 0; rg < 4; rg++) {
            int rr = quad * 4 + rg;
            float S1 = redbuf[pp][0][rr][0] + redbuf[pp][1][rr][0]
                     + redbuf[pp][2][rr][0] + redbuf[pp][3][rr][0];
            float S2 = redbuf[pp][0][rr][1] + redbuf[pp][1][rr][1]
                     + redbuf[pp][2][rr][1] + redbuf[pp][3][rr][1];
            tau[rg] += (S2 - 1.f) * 0.5f * __builtin_amdgcn_rcpf(S1);
        }
        pp ^= 1;
    }

    // ---- P = relu(z-tau)^2 -> P_lds (bf16, A-operand layout [row][j]) ----
    #pragma unroll
    for (int fi = 0; fi < 16; fi++) {
        int sup = fi >> 1, jj = fi & 1;
        int jbase = sup * 128 + (wv + 4 * jj) * 16;
        #pragma unroll
        for (int rg = 0; rg < 4; rg++) {
            float r = fmaxf(zf[fi][rg] - tau[rg], 0.f);
            P_lds[(quad * 4 + rg) * 1032 + jbase + l16] = (short)f2bf(r * r);
        }
    }
    __syncthreads();

    // ---- PV straight from global V^T: O[r][d] += P[r][j] V[j][d] ----
    f32x4 oacc[4];
    #pragma unroll
    for (int nt = 0; nt < 4; nt++) oacc[nt] = (f32x4){0.f, 0.f, 0.f, 0.f};
    const short* vb0 = vt + (size_t)((bb * 8 + hh) * 64) * 1024;
    #pragma unroll
    for (int sup = 0; sup < 8; sup++) {
        bf16x8 pf = *(const bf16x8*)(P_lds + l16 * 1032 + sup * 128 + wv * 32 + quad * 8);
        #pragma unroll
        for (int nt = 0; nt < 4; nt++) {
            bf16x8 bv = *(const bf16x8*)(vb0 + (size_t)(nt * 16 + l16) * 1024
                                         + sup * 128 + wv * 32 + quad * 8);
            oacc[nt] = __builtin_amdgcn_mfma_f32_16x16x32_bf16(pf, bv, oacc[nt], 0, 0, 0);
        }
    }
    __syncthreads();   // all P reads done; overlay osum on P_lds

    #pragma unroll
    for (int nt = 0; nt < 4; nt++)
        #pragma unroll
        for (int rg = 0; rg < 4; rg++)
            osum[(wv * 16 + quad * 4 + rg) * 68 + nt * 16 + l16] = oacc[nt][rg];
    __syncthreads();
    #pragma unroll
    for (int i = 0; i < 2; i++) {
        int idx = t + 256 * i;              // 512 col-pair tasks
        int r = idx >> 5, dp = idx & 31;
        float e0 = 0.f, e1 = 0.f;
        #pragma unroll
        for (int w = 0; w < 4; w++) {
            e0 += osum[(w * 16 + r) * 68 + dp * 2];
            e1 += osum[(w * 16 + r) * 68 + dp * 2 + 1];
        }
        *(uint32_t*)(oheads + (size_t)(bb * 1024 + r0 + r) * 512 + hh * 64 + dp * 2) = packbf2(e0, e1);
    }
}

// ---------------------------------------------------------------------------
extern "C" void kernel_launch(void* const* d_in, const int* in_sizes, int n_in,
                              void* d_out, int out_size, void* d_ws, size_t ws_size,
                              hipStream_t stream) {
    (void)in_sizes; (void)n_in; (void)out_size; (void)ws_size;
    const float* x     = (const float*)d_in[0];
    const float* w_qkv = (const float*)d_in[1];
    const float* w_out = (const float*)d_in[2];
    float* out = (float*)d_out;

    char* ws = (char*)d_ws;
    short* qkv_b  = (short*)(ws);                        // 8,388,608 B  (Q|K)
    short* vt     = (short*)(ws + 8388608);              // 4,194,304 B  (V^T)
    short* ohead  = (short*)(ws + 12582912);             // 4,194,304 B
    short* xb     = (short*)(ws + 16777216);             // 4,194,304 B
    short* wqkvt  = (short*)(ws + 20971520);             // 1,572,864 B
    short* woutt  = (short*)(ws + 22544384);             //   524,288 B

    convert_all<<<dim3(2048), dim3(256), 0, stream>>>(x, w_qkv, w_out, xb, wqkvt, woutt);
    gemm_bf16<12, 0><<<dim3(64 * 12), dim3(256), 0, stream>>>(xb, wqkvt, (void*)qkv_b, vt);
    attn_entmax<<<dim3(2048), dim3(256), 0, stream>>>(qkv_b, vt, ohead);
    gemm_bf16<4, 1><<<dim3(64 * 4), dim3(256), 0, stream>>>(ohead, woutt, (void*)out, nullptr);
}